// Round 1
// baseline (64750.043 us; speedup 1.0000x reference)
//
#include <hip/hip_runtime.h>
#include <math.h>

#define BB 256
#define TT 256
#define HH 512
#define G4 2048
#define IN0_ 519

__device__ __forceinline__ float sigf(float x) { return 1.0f / (1.0f + expf(-x)); }
__device__ __forceinline__ float leaky(float x) { return x > 0.f ? x : 0.2f * x; }

__device__ __forceinline__ float block_sum(float v, float* red, int tid) {
    red[tid] = v; __syncthreads();
    for (int s = 128; s > 0; s >>= 1) {
        if (tid < s) red[tid] += red[tid + s];
        __syncthreads();
    }
    float r = red[0];
    __syncthreads();
    return r;
}

// ---------------- init: zero states, pos=start, cur=init_in, lengths ----------------
__global__ void init_kernel(const float* __restrict__ start,
                            const float* __restrict__ init_in,
                            const int* __restrict__ max_len,
                            float* __restrict__ h0, float* __restrict__ c0,
                            float* __restrict__ h1, float* __restrict__ c1,
                            float* __restrict__ pos, float* __restrict__ cur,
                            float* __restrict__ out_tail)
{
    int i = blockIdx.x * blockDim.x + threadIdx.x;
    if (i < BB * HH) { h0[i] = 0.f; c0[i] = 0.f; h1[i] = 0.f; c1[i] = 0.f; }
    if (i < BB * 2) pos[i] = start[i];
    if (i < BB * 3) cur[i] = init_in[i % 3];
    if (i < BB)     out_tail[i] = (float)max_len[0];
}

// ---------------- condition encoder: one block per batch row ----------------
__global__ __launch_bounds__(256) void cond_encoder(
    const float* __restrict__ start, const float* __restrict__ end,
    const float* __restrict__ z,
    const float* __restrict__ w1, const float* __restrict__ b1,
    const float* __restrict__ g1, const float* __restrict__ be1,
    const float* __restrict__ w2, const float* __restrict__ b2,
    const float* __restrict__ g2, const float* __restrict__ be2,
    float* __restrict__ cond)
{
    __shared__ float ci[70];
    __shared__ float xr[512];
    __shared__ float red[256];
    int b = blockIdx.x, tid = threadIdx.x;
    if (tid == 0) {
        float sx = start[2*b], sy = start[2*b+1];
        float ex = end[2*b],   ey = end[2*b+1];
        float dx = ex - sx, dy = ey - sy;
        ci[0]=sx; ci[1]=sy; ci[2]=ex; ci[3]=ey;
        ci[4]=sqrtf(dx*dx + dy*dy + 1e-8f);
        ci[5]=atan2f(dy, dx);
    }
    if (tid < 64) ci[6+tid] = z[b*64 + tid];
    __syncthreads();

    // phase 1: pre = ci @ w1^T + b1  (each thread: rows tid, tid+256)
    float pre0 = b1[tid], pre1 = b1[tid+256];
    {
        const float* r0 = w1 + (size_t)tid*70;
        const float* r1 = w1 + (size_t)(tid+256)*70;
        for (int k = 0; k < 70; k++) { float c = ci[k]; pre0 += c*r0[k]; pre1 += c*r1[k]; }
    }
    float m = block_sum(pre0+pre1, red, tid) * (1.f/512.f);
    float d0 = pre0-m, d1 = pre1-m;
    float v = block_sum(d0*d0 + d1*d1, red, tid) * (1.f/512.f);
    float rstd = rsqrtf(v + 1e-5f);
    xr[tid]     = leaky(d0*rstd*g1[tid]     + be1[tid]);
    xr[tid+256] = leaky(d1*rstd*g1[tid+256] + be1[tid+256]);
    __syncthreads();

    // phase 2: pre2 = x @ w2^T + b2
    float q0 = b2[tid], q1 = b2[tid+256];
    {
        const float4* r0 = (const float4*)(w2 + (size_t)tid*512);
        const float4* r1 = (const float4*)(w2 + (size_t)(tid+256)*512);
        const float4* xv4 = (const float4*)xr;
        for (int q = 0; q < 128; q++) {
            float4 xv = xv4[q];
            float4 wa = r0[q], wb = r1[q];
            q0 += xv.x*wa.x + xv.y*wa.y + xv.z*wa.z + xv.w*wa.w;
            q1 += xv.x*wb.x + xv.y*wb.y + xv.z*wb.z + xv.w*wb.w;
        }
    }
    m = block_sum(q0+q1, red, tid) * (1.f/512.f);
    d0 = q0-m; d1 = q1-m;
    v = block_sum(d0*d0 + d1*d1, red, tid) * (1.f/512.f);
    rstd = rsqrtf(v + 1e-5f);
    cond[(size_t)b*512 + tid]     = leaky(d0*rstd*g2[tid]     + be2[tid]);
    cond[(size_t)b*512 + tid+256] = leaky(d1*rstd*g2[tid+256] + be2[tid+256]);
}

// ---------------- static part of layer-0 gates: gs0 = cond @ Wih0[:,3:515]^T + bih0 + bhh0 ----------------
__global__ __launch_bounds__(256) void static_gates(
    const float* __restrict__ cond, const float* __restrict__ Wih0,
    const float* __restrict__ bih0, const float* __restrict__ bhh0,
    float* __restrict__ gs0)
{
    __shared__ float As[16][17];
    __shared__ float Bs[16][17];
    int tx = threadIdx.x & 15, ty = threadIdx.x >> 4;
    int brow = blockIdx.x * 16;
    int jcol = blockIdx.y * 16;
    float acc = 0.f;
    for (int kt = 0; kt < 512; kt += 16) {
        As[ty][tx] = cond[(size_t)(brow+ty)*512 + kt + tx];
        Bs[ty][tx] = Wih0[(size_t)(jcol+ty)*IN0_ + 3 + kt + tx];
        __syncthreads();
        #pragma unroll
        for (int kk = 0; kk < 16; kk++) acc += As[ty][kk] * Bs[tx][kk];
        __syncthreads();
    }
    int jg = jcol + tx;
    gs0[(size_t)(brow+ty)*G4 + jg] = acc + bih0[jg] + bhh0[jg];
}

// ---------------- GEMM accumulate helper: acc[g][r] += src[b] . W[g*512+j] ----------------
__device__ __forceinline__ void accum_block(
    float (&acc)[4][2], const float* __restrict__ W,
    const float* __restrict__ src, int b0, int j, int tx, int ty, int tid,
    float* __restrict__ hsh /* [32*68] */)
{
    for (int kt = 0; kt < 512; kt += 64) {
        __syncthreads();
        #pragma unroll
        for (int r = 0; r < 2; r++) {
            int f = tid + r*256;
            int bb = f >> 4;
            int kq = f & 15;
            float4 vv = *(const float4*)&src[(size_t)(b0+bb)*HH + kt + kq*4];
            *(float4*)&hsh[bb*68 + kq*4] = vv;
        }
        __syncthreads();
        const float4* w0 = (const float4*)&W[(size_t)(0*HH + j)*HH + kt];
        const float4* w1 = (const float4*)&W[(size_t)(1*HH + j)*HH + kt];
        const float4* w2 = (const float4*)&W[(size_t)(2*HH + j)*HH + kt];
        const float4* w3 = (const float4*)&W[(size_t)(3*HH + j)*HH + kt];
        const float* a1p = &hsh[ty*68];
        const float* a2p = &hsh[(ty+16)*68];
        #pragma unroll
        for (int q = 0; q < 16; q++) {
            float4 a1 = *(const float4*)&a1p[q*4];
            float4 a2 = *(const float4*)&a2p[q*4];
            float4 wa = w0[q], wb = w1[q], wc = w2[q], wd = w3[q];
            acc[0][0] += a1.x*wa.x + a1.y*wa.y + a1.z*wa.z + a1.w*wa.w;
            acc[0][1] += a2.x*wa.x + a2.y*wa.y + a2.z*wa.z + a2.w*wa.w;
            acc[1][0] += a1.x*wb.x + a1.y*wb.y + a1.z*wb.z + a1.w*wb.w;
            acc[1][1] += a2.x*wb.x + a2.y*wb.y + a2.z*wb.z + a2.w*wb.w;
            acc[2][0] += a1.x*wc.x + a1.y*wc.y + a1.z*wc.z + a1.w*wc.w;
            acc[2][1] += a2.x*wc.x + a2.y*wc.y + a2.z*wc.z + a2.w*wc.w;
            acc[3][0] += a1.x*wd.x + a1.y*wd.y + a1.z*wd.z + a1.w*wd.w;
            acc[3][1] += a2.x*wd.x + a2.y*wd.y + a2.z*wd.z + a2.w*wd.w;
        }
    }
}

// ---------------- per-step layer 0 ----------------
__global__ __launch_bounds__(256) void step0_kernel(
    const float* __restrict__ gs0, const float* __restrict__ Wih0,
    const float* __restrict__ Whh0,
    const float* __restrict__ end, const float* __restrict__ pos,
    const float* __restrict__ cur,
    const float* __restrict__ h_in, const float* __restrict__ c_in,
    float* __restrict__ h_out, float* __restrict__ c_out)
{
    __shared__ float hsh[32*68];
    __shared__ float feats[32][8];
    int tid = threadIdx.x;
    int tx = tid & 15, ty = tid >> 4;
    int b0 = blockIdx.x * 32;
    int j  = blockIdx.y * 16 + tx;
    if (tid < 32) {
        int b = b0 + tid;
        float px = pos[2*b], py = pos[2*b+1];
        float ex = end[2*b], ey = end[2*b+1];
        float rx = ex - px, ry = ey - py;
        feats[tid][0] = cur[3*b];
        feats[tid][1] = cur[3*b+1];
        feats[tid][2] = cur[3*b+2];
        feats[tid][3] = rx;
        feats[tid][4] = ry;
        feats[tid][5] = sqrtf(rx*rx + ry*ry + 1e-8f);
        feats[tid][6] = atan2f(ry, rx);
    }
    float acc[4][2];
    #pragma unroll
    for (int g = 0; g < 4; g++) {
        acc[g][0] = gs0[(size_t)(b0+ty)*G4    + g*HH + j];
        acc[g][1] = gs0[(size_t)(b0+ty+16)*G4 + g*HH + j];
    }
    accum_block(acc, Whh0, h_in, b0, j, tx, ty, tid, hsh);

    const int fcol[7] = {0, 1, 2, 515, 516, 517, 518};
    #pragma unroll
    for (int g = 0; g < 4; g++) {
        const float* wr = Wih0 + (size_t)(g*HH + j)*IN0_;
        #pragma unroll
        for (int f = 0; f < 7; f++) {
            float w = wr[fcol[f]];
            acc[g][0] += feats[ty][f]    * w;
            acc[g][1] += feats[ty+16][f] * w;
        }
    }
    #pragma unroll
    for (int r = 0; r < 2; r++) {
        int b = b0 + ty + r*16;
        float ig = sigf(acc[0][r]);
        float fg = sigf(acc[1][r]);
        float gg = tanhf(acc[2][r]);
        float og = sigf(acc[3][r]);
        float cold = c_in[(size_t)b*HH + j];
        float cn = fg*cold + ig*gg;
        c_out[(size_t)b*HH + j] = cn;
        h_out[(size_t)b*HH + j] = og * tanhf(cn);
    }
}

// ---------------- per-step layer 1 ----------------
__global__ __launch_bounds__(256) void step1_kernel(
    const float* __restrict__ bih1, const float* __restrict__ bhh1,
    const float* __restrict__ Wih1, const float* __restrict__ Whh1,
    const float* __restrict__ x,
    const float* __restrict__ h_in, const float* __restrict__ c_in,
    float* __restrict__ h_out, float* __restrict__ c_out)
{
    __shared__ float hsh[32*68];
    int tid = threadIdx.x;
    int tx = tid & 15, ty = tid >> 4;
    int b0 = blockIdx.x * 32;
    int j  = blockIdx.y * 16 + tx;
    float acc[4][2];
    #pragma unroll
    for (int g = 0; g < 4; g++) {
        float bs = bih1[g*HH + j] + bhh1[g*HH + j];
        acc[g][0] = bs; acc[g][1] = bs;
    }
    accum_block(acc, Wih1, x,    b0, j, tx, ty, tid, hsh);
    accum_block(acc, Whh1, h_in, b0, j, tx, ty, tid, hsh);
    #pragma unroll
    for (int r = 0; r < 2; r++) {
        int b = b0 + ty + r*16;
        float ig = sigf(acc[0][r]);
        float fg = sigf(acc[1][r]);
        float gg = tanhf(acc[2][r]);
        float og = sigf(acc[3][r]);
        float cold = c_in[(size_t)b*HH + j];
        float cn = fg*cold + ig*gg;
        c_out[(size_t)b*HH + j] = cn;
        h_out[(size_t)b*HH + j] = og * tanhf(cn);
    }
}

// ---------------- head: o = leaky(h2@ow1^T+ob1)@ow2^T+ob2; out, pos, cur ----------------
__global__ __launch_bounds__(256) void head_kernel(
    const float* __restrict__ h2,
    const float* __restrict__ ow1, const float* __restrict__ ob1,
    const float* __restrict__ ow2, const float* __restrict__ ob2,
    float* __restrict__ outputs, float* __restrict__ pos, float* __restrict__ cur,
    int t)
{
    __shared__ float h2s[4][512];
    __shared__ float hid[4][256];
    __shared__ float osh[4][3];
    int tid = threadIdx.x;
    int b0 = blockIdx.x * 4;
    #pragma unroll
    for (int r = 0; r < 8; r++) {
        int idx = tid + r*256;
        int bi = idx >> 9, k = idx & 511;
        h2s[bi][k] = h2[(size_t)(b0+bi)*HH + k];
    }
    __syncthreads();
    float acc0 = ob1[tid], acc1 = acc0, acc2 = acc0, acc3 = acc0;
    {
        const float4* w4 = (const float4*)(ow1 + (size_t)tid*512);
        #pragma unroll 4
        for (int q = 0; q < 128; q++) {
            float4 w = w4[q];
            float4 a0 = *(const float4*)&h2s[0][q*4];
            float4 a1 = *(const float4*)&h2s[1][q*4];
            float4 a2 = *(const float4*)&h2s[2][q*4];
            float4 a3 = *(const float4*)&h2s[3][q*4];
            acc0 += a0.x*w.x + a0.y*w.y + a0.z*w.z + a0.w*w.w;
            acc1 += a1.x*w.x + a1.y*w.y + a1.z*w.z + a1.w*w.w;
            acc2 += a2.x*w.x + a2.y*w.y + a2.z*w.z + a2.w*w.w;
            acc3 += a3.x*w.x + a3.y*w.y + a3.z*w.z + a3.w*w.w;
        }
    }
    hid[0][tid] = leaky(acc0);
    hid[1][tid] = leaky(acc1);
    hid[2][tid] = leaky(acc2);
    hid[3][tid] = leaky(acc3);
    __syncthreads();
    int wave = tid >> 6, lane = tid & 63;
    #pragma unroll
    for (int r = 0; r < 3; r++) {
        float p = 0.f;
        #pragma unroll
        for (int q = 0; q < 4; q++) {
            int k = lane + q*64;
            p += hid[wave][k] * ow2[r*256 + k];
        }
        for (int off = 32; off; off >>= 1) p += __shfl_down(p, off);
        if (lane == 0) osh[wave][r] = p + ob2[r];
    }
    __syncthreads();
    if (tid < 4) {
        int b = b0 + tid;
        float o0 = osh[tid][0], o1 = osh[tid][1], o2 = osh[tid][2];
        float sp = (o2 > 20.f ? o2 : log1pf(expf(o2))) + 0.001f;
        float* op = outputs + ((size_t)b*TT + t)*3;
        op[0] = o0; op[1] = o1; op[2] = sp;
        pos[2*b]   += o0;
        pos[2*b+1] += o1;
        cur[3*b] = o0; cur[3*b+1] = o1; cur[3*b+2] = sp;
    }
}

extern "C" void kernel_launch(void* const* d_in, const int* in_sizes, int n_in,
                              void* d_out, int out_size, void* d_ws, size_t ws_size,
                              hipStream_t stream)
{
    const float* start  = (const float*)d_in[0];
    const float* end    = (const float*)d_in[1];
    const float* z      = (const float*)d_in[2];
    const float* ce_w1  = (const float*)d_in[3];
    const float* ce_b1  = (const float*)d_in[4];
    const float* ce_g1  = (const float*)d_in[5];
    const float* ce_be1 = (const float*)d_in[6];
    const float* ce_w2  = (const float*)d_in[7];
    const float* ce_b2  = (const float*)d_in[8];
    const float* ce_g2  = (const float*)d_in[9];
    const float* ce_be2 = (const float*)d_in[10];
    const float* Wih0   = (const float*)d_in[11];
    const float* Whh0   = (const float*)d_in[12];
    const float* bih0   = (const float*)d_in[13];
    const float* bhh0   = (const float*)d_in[14];
    const float* Wih1   = (const float*)d_in[15];
    const float* Whh1   = (const float*)d_in[16];
    const float* bih1   = (const float*)d_in[17];
    const float* bhh1   = (const float*)d_in[18];
    const float* ow1    = (const float*)d_in[19];
    const float* ob1    = (const float*)d_in[20];
    const float* ow2    = (const float*)d_in[21];
    const float* ob2    = (const float*)d_in[22];
    const float* init_in= (const float*)d_in[23];
    const int*   max_len= (const int*)d_in[24];

    float* out = (float*)d_out;
    float* ws  = (float*)d_ws;
    size_t off = 0;
    float* cond = ws + off; off += (size_t)BB*HH;
    float* gs0  = ws + off; off += (size_t)BB*G4;
    float* h0b[2]; h0b[0] = ws + off; off += (size_t)BB*HH; h0b[1] = ws + off; off += (size_t)BB*HH;
    float* c0b[2]; c0b[0] = ws + off; off += (size_t)BB*HH; c0b[1] = ws + off; off += (size_t)BB*HH;
    float* h1b[2]; h1b[0] = ws + off; off += (size_t)BB*HH; h1b[1] = ws + off; off += (size_t)BB*HH;
    float* c1b[2]; c1b[0] = ws + off; off += (size_t)BB*HH; c1b[1] = ws + off; off += (size_t)BB*HH;
    float* pos  = ws + off; off += (size_t)BB*2;
    float* cur  = ws + off; off += (size_t)BB*3;

    init_kernel<<<dim3((BB*HH + 255)/256), dim3(256), 0, stream>>>(
        start, init_in, max_len, h0b[0], c0b[0], h1b[0], c1b[0], pos, cur,
        out + (size_t)BB*TT*3);
    cond_encoder<<<dim3(BB), dim3(256), 0, stream>>>(
        start, end, z, ce_w1, ce_b1, ce_g1, ce_be1, ce_w2, ce_b2, ce_g2, ce_be2, cond);
    static_gates<<<dim3(16, 128), dim3(256), 0, stream>>>(cond, Wih0, bih0, bhh0, gs0);

    for (int t = 0; t < TT; t++) {
        int p = t & 1, np = p ^ 1;
        step0_kernel<<<dim3(8, 32), dim3(256), 0, stream>>>(
            gs0, Wih0, Whh0, end, pos, cur, h0b[p], c0b[p], h0b[np], c0b[np]);
        step1_kernel<<<dim3(8, 32), dim3(256), 0, stream>>>(
            bih1, bhh1, Wih1, Whh1, h0b[np], h1b[p], c1b[p], h1b[np], c1b[np]);
        head_kernel<<<dim3(64), dim3(256), 0, stream>>>(
            h1b[np], ow1, ob1, ow2, ob2, out, pos, cur, t);
    }
}

// Round 3
// 12002.589 us; speedup vs baseline: 5.3947x; 5.3947x over previous
//
#include <hip/hip_runtime.h>
#include <math.h>

#define BB 256
#define TT 256
#define HH 512
#define G4 2048
#define IN0_ 519

typedef __bf16 bf16x8 __attribute__((ext_vector_type(8)));
typedef float  f32x4  __attribute__((ext_vector_type(4)));

__device__ __forceinline__ float sigf(float x) { return 1.0f / (1.0f + expf(-x)); }
__device__ __forceinline__ float leaky(float x) { return x > 0.f ? x : 0.2f * x; }

__device__ __forceinline__ unsigned short f2b(float x) {
    union { float f; unsigned int u; } v; v.f = x;
    unsigned int r = v.u + 0x7fffu + ((v.u >> 16) & 1u);   // RNE
    return (unsigned short)(r >> 16);
}

__device__ __forceinline__ float block_sum(float v, float* red, int tid) {
    red[tid] = v; __syncthreads();
    for (int s = 128; s > 0; s >>= 1) {
        if (tid < s) red[tid] += red[tid + s];
        __syncthreads();
    }
    float r = red[0];
    __syncthreads();
    return r;
}

// ---------------- one-time: weights fp32 -> bf16, pack feature columns ----------------
__global__ __launch_bounds__(256) void prep_weights(
    const float* __restrict__ Whh0, const float* __restrict__ Wih1,
    const float* __restrict__ Whh1, const float* __restrict__ Wih0,
    unsigned short* __restrict__ w0b, unsigned short* __restrict__ w1b,
    unsigned short* __restrict__ w2b, float* __restrict__ Wf)
{
    int idx = blockIdx.x * 256 + threadIdx.x;
    if (idx < G4 * HH) {
        w0b[idx] = f2b(Whh0[idx]);
        w1b[idx] = f2b(Wih1[idx]);
        w2b[idx] = f2b(Whh1[idx]);
    }
    if (idx < G4) {
        const int fc[7] = {0, 1, 2, 515, 516, 517, 518};
        #pragma unroll
        for (int f = 0; f < 7; f++) Wf[idx*8 + f] = Wih0[(size_t)idx*IN0_ + fc[f]];
        Wf[idx*8 + 7] = 0.f;
    }
}

// ---------------- init: zero states, pos=start, cur=init_in, lengths ----------------
__global__ void init_kernel(const float* __restrict__ start,
                            const float* __restrict__ init_in,
                            const int* __restrict__ max_len,
                            float* __restrict__ c0, float* __restrict__ c1,
                            unsigned short* __restrict__ h0u, unsigned short* __restrict__ h1u,
                            float* __restrict__ pos, float* __restrict__ cur,
                            float* __restrict__ out_tail)
{
    int i = blockIdx.x * blockDim.x + threadIdx.x;
    if (i < BB * HH) { c0[i] = 0.f; c1[i] = 0.f; h0u[i] = 0; h1u[i] = 0; }
    if (i < BB * 2) pos[i] = start[i];
    if (i < BB * 3) cur[i] = init_in[i % 3];
    if (i < BB)     out_tail[i] = (float)max_len[0];
}

// ---------------- condition encoder: one block per batch row ----------------
__global__ __launch_bounds__(256) void cond_encoder(
    const float* __restrict__ start, const float* __restrict__ end,
    const float* __restrict__ z,
    const float* __restrict__ w1, const float* __restrict__ b1,
    const float* __restrict__ g1, const float* __restrict__ be1,
    const float* __restrict__ w2, const float* __restrict__ b2,
    const float* __restrict__ g2, const float* __restrict__ be2,
    float* __restrict__ cond)
{
    __shared__ float ci[70];
    __shared__ float xr[512];
    __shared__ float red[256];
    int b = blockIdx.x, tid = threadIdx.x;
    if (tid == 0) {
        float sx = start[2*b], sy = start[2*b+1];
        float ex = end[2*b],   ey = end[2*b+1];
        float dx = ex - sx, dy = ey - sy;
        ci[0]=sx; ci[1]=sy; ci[2]=ex; ci[3]=ey;
        ci[4]=sqrtf(dx*dx + dy*dy + 1e-8f);
        ci[5]=atan2f(dy, dx);
    }
    if (tid < 64) ci[6+tid] = z[b*64 + tid];
    __syncthreads();

    float pre0 = b1[tid], pre1 = b1[tid+256];
    {
        const float* r0 = w1 + (size_t)tid*70;
        const float* r1 = w1 + (size_t)(tid+256)*70;
        for (int k = 0; k < 70; k++) { float c = ci[k]; pre0 += c*r0[k]; pre1 += c*r1[k]; }
    }
    float m = block_sum(pre0+pre1, red, tid) * (1.f/512.f);
    float d0 = pre0-m, d1 = pre1-m;
    float v = block_sum(d0*d0 + d1*d1, red, tid) * (1.f/512.f);
    float rstd = rsqrtf(v + 1e-5f);
    xr[tid]     = leaky(d0*rstd*g1[tid]     + be1[tid]);
    xr[tid+256] = leaky(d1*rstd*g1[tid+256] + be1[tid+256]);
    __syncthreads();

    float q0 = b2[tid], q1 = b2[tid+256];
    {
        const float4* r0 = (const float4*)(w2 + (size_t)tid*512);
        const float4* r1 = (const float4*)(w2 + (size_t)(tid+256)*512);
        const float4* xv4 = (const float4*)xr;
        for (int q = 0; q < 128; q++) {
            float4 xv = xv4[q];
            float4 wa = r0[q], wb = r1[q];
            q0 += xv.x*wa.x + xv.y*wa.y + xv.z*wa.z + xv.w*wa.w;
            q1 += xv.x*wb.x + xv.y*wb.y + xv.z*wb.z + xv.w*wb.w;
        }
    }
    m = block_sum(q0+q1, red, tid) * (1.f/512.f);
    d0 = q0-m; d1 = q1-m;
    v = block_sum(d0*d0 + d1*d1, red, tid) * (1.f/512.f);
    rstd = rsqrtf(v + 1e-5f);
    cond[(size_t)b*512 + tid]     = leaky(d0*rstd*g2[tid]     + be2[tid]);
    cond[(size_t)b*512 + tid+256] = leaky(d1*rstd*g2[tid+256] + be2[tid+256]);
}

// ---------------- static gates: gs0 = cond @ Wih0[:,3:515]^T + bih0 + bhh0 ----------------
__global__ __launch_bounds__(256) void static_gates(
    const float* __restrict__ cond, const float* __restrict__ Wih0,
    const float* __restrict__ bih0, const float* __restrict__ bhh0,
    float* __restrict__ gs0)
{
    __shared__ float As[16][17];
    __shared__ float Bs[16][17];
    int tx = threadIdx.x & 15, ty = threadIdx.x >> 4;
    int brow = blockIdx.x * 16;
    int jcol = blockIdx.y * 16;
    float acc = 0.f;
    for (int kt = 0; kt < 512; kt += 16) {
        As[ty][tx] = cond[(size_t)(brow+ty)*512 + kt + tx];
        Bs[ty][tx] = Wih0[(size_t)(jcol+ty)*IN0_ + 3 + kt + tx];
        __syncthreads();
        #pragma unroll
        for (int kk = 0; kk < 16; kk++) acc += As[ty][kk] * Bs[tx][kk];
        __syncthreads();
    }
    int jg = jcol + tx;
    gs0[(size_t)(brow+ty)*G4 + jg] = acc + bih0[jg] + bhh0[jg];
}

// ---------------- per-step layer 0 (MFMA): gates = gs0 + h@Whh0^T + feats@Wf^T ----------------
__global__ __launch_bounds__(256) void lstm0_mfma(
    const unsigned short* __restrict__ Wb,   // Whh0 bf16 [2048][512]
    const float* __restrict__ gs0,           // [256][2048]
    const float* __restrict__ Wf,            // [2048][8]
    const float* __restrict__ end, const float* __restrict__ pos,
    const float* __restrict__ cur,
    const unsigned short* __restrict__ h_in, // bf16 [256][512]
    const float* __restrict__ c_in,
    float* __restrict__ c_out,
    unsigned short* __restrict__ h_out)
{
    __shared__ float ct[4][16][16];
    __shared__ float feats[16][8];
    int tid = threadIdx.x;
    int w = tid >> 6, l = tid & 63;
    int lr = l & 15, lk = l >> 4;
    int m0 = blockIdx.x * 16;
    int n0 = blockIdx.y * 16;
    if (tid < 16) {
        int b = m0 + tid;
        float px = pos[2*b], py = pos[2*b+1];
        float ex = end[2*b], ey = end[2*b+1];
        float rx = ex - px, ry = ey - py;
        feats[tid][0] = cur[3*b];
        feats[tid][1] = cur[3*b+1];
        feats[tid][2] = cur[3*b+2];
        feats[tid][3] = rx;
        feats[tid][4] = ry;
        feats[tid][5] = sqrtf(rx*rx + ry*ry + 1e-8f);
        feats[tid][6] = atan2f(ry, rx);
        feats[tid][7] = 0.f;
    }
    int jg = w*512 + n0 + lr;                 // global gate column in [0,2048)
    f32x4 acc;
    #pragma unroll
    for (int r = 0; r < 4; r++)
        acc[r] = gs0[(size_t)(m0 + lk*4 + r)*G4 + jg];
    const unsigned short* ap = h_in + (size_t)(m0 + lr)*HH + lk*8;
    const unsigned short* bp = Wb   + (size_t)jg*HH + lk*8;
    #pragma unroll
    for (int kt = 0; kt < 16; kt++) {
        bf16x8 a = *reinterpret_cast<const bf16x8*>(ap + kt*32);
        bf16x8 b = *reinterpret_cast<const bf16x8*>(bp + kt*32);
        acc = __builtin_amdgcn_mfma_f32_16x16x32_bf16(a, b, acc, 0, 0, 0);
    }
    #pragma unroll
    for (int r = 0; r < 4; r++) ct[w][lk*4 + r][lr] = acc[r];
    __syncthreads();

    int bl = tid >> 4, jl = tid & 15;
    int b = m0 + bl;
    int j = n0 + jl;
    float g4[4];
    #pragma unroll
    for (int g = 0; g < 4; g++) {
        float v = ct[g][bl][jl];
        const float* wf = Wf + (size_t)(g*HH + j)*8;
        #pragma unroll
        for (int f = 0; f < 7; f++) v += feats[bl][f] * wf[f];
        g4[g] = v;
    }
    float ig = sigf(g4[0]), fg = sigf(g4[1]);
    float gg = tanhf(g4[2]), og = sigf(g4[3]);
    float cn = fg * c_in[(size_t)b*HH + j] + ig * gg;
    c_out[(size_t)b*HH + j] = cn;
    h_out[(size_t)b*HH + j] = f2b(og * tanhf(cn));
}

// ---------------- per-step layer 1 (MFMA): gates = b + x@Wih1^T + h@Whh1^T ----------------
__global__ __launch_bounds__(256) void lstm1_mfma(
    const unsigned short* __restrict__ Wi,   // Wih1 bf16 [2048][512]
    const unsigned short* __restrict__ Wh,   // Whh1 bf16 [2048][512]
    const float* __restrict__ bi, const float* __restrict__ bh,
    const unsigned short* __restrict__ x,    // h0 bf16
    const unsigned short* __restrict__ h_in, // h1_prev bf16
    const float* __restrict__ c_in,
    float* __restrict__ c_out,
    unsigned short* __restrict__ h_out, float* __restrict__ h_out_f)
{
    __shared__ float ct[4][16][16];
    int tid = threadIdx.x;
    int w = tid >> 6, l = tid & 63;
    int lr = l & 15, lk = l >> 4;
    int m0 = blockIdx.x * 16;
    int n0 = blockIdx.y * 16;
    int jg = w*512 + n0 + lr;
    float bs = bi[jg] + bh[jg];
    f32x4 acc;
    #pragma unroll
    for (int r = 0; r < 4; r++) acc[r] = bs;
    {
        const unsigned short* ap = x  + (size_t)(m0 + lr)*HH + lk*8;
        const unsigned short* bp = Wi + (size_t)jg*HH + lk*8;
        #pragma unroll
        for (int kt = 0; kt < 16; kt++) {
            bf16x8 a = *reinterpret_cast<const bf16x8*>(ap + kt*32);
            bf16x8 b = *reinterpret_cast<const bf16x8*>(bp + kt*32);
            acc = __builtin_amdgcn_mfma_f32_16x16x32_bf16(a, b, acc, 0, 0, 0);
        }
    }
    {
        const unsigned short* ap = h_in + (size_t)(m0 + lr)*HH + lk*8;
        const unsigned short* bp = Wh   + (size_t)jg*HH + lk*8;
        #pragma unroll
        for (int kt = 0; kt < 16; kt++) {
            bf16x8 a = *reinterpret_cast<const bf16x8*>(ap + kt*32);
            bf16x8 b = *reinterpret_cast<const bf16x8*>(bp + kt*32);
            acc = __builtin_amdgcn_mfma_f32_16x16x32_bf16(a, b, acc, 0, 0, 0);
        }
    }
    #pragma unroll
    for (int r = 0; r < 4; r++) ct[w][lk*4 + r][lr] = acc[r];
    __syncthreads();

    int bl = tid >> 4, jl = tid & 15;
    int b = m0 + bl;
    int j = n0 + jl;
    float ig = sigf(ct[0][bl][jl]), fg = sigf(ct[1][bl][jl]);
    float gg = tanhf(ct[2][bl][jl]), og = sigf(ct[3][bl][jl]);
    float cn = fg * c_in[(size_t)b*HH + j] + ig * gg;
    c_out[(size_t)b*HH + j] = cn;
    float hv = og * tanhf(cn);
    h_out[(size_t)b*HH + j] = f2b(hv);
    h_out_f[(size_t)b*HH + j] = hv;
}

// ---------------- head: o = leaky(h2@ow1^T+ob1)@ow2^T+ob2; out, pos, cur ----------------
__global__ __launch_bounds__(256) void head_kernel(
    const float* __restrict__ h2,
    const float* __restrict__ ow1, const float* __restrict__ ob1,
    const float* __restrict__ ow2, const float* __restrict__ ob2,
    float* __restrict__ outputs, float* __restrict__ pos, float* __restrict__ cur,
    int t)
{
    __shared__ float h2s[4][512];
    __shared__ float hid[4][256];
    __shared__ float osh[4][3];
    int tid = threadIdx.x;
    int b0 = blockIdx.x * 4;
    #pragma unroll
    for (int r = 0; r < 8; r++) {
        int idx = tid + r*256;
        int bi = idx >> 9, k = idx & 511;
        h2s[bi][k] = h2[(size_t)(b0+bi)*HH + k];
    }
    __syncthreads();
    float acc0 = ob1[tid], acc1 = acc0, acc2 = acc0, acc3 = acc0;
    {
        const float4* w4 = (const float4*)(ow1 + (size_t)tid*512);
        #pragma unroll 4
        for (int q = 0; q < 128; q++) {
            float4 w = w4[q];
            float4 a0 = *(const float4*)&h2s[0][q*4];
            float4 a1 = *(const float4*)&h2s[1][q*4];
            float4 a2 = *(const float4*)&h2s[2][q*4];
            float4 a3 = *(const float4*)&h2s[3][q*4];
            acc0 += a0.x*w.x + a0.y*w.y + a0.z*w.z + a0.w*w.w;
            acc1 += a1.x*w.x + a1.y*w.y + a1.z*w.z + a1.w*w.w;
            acc2 += a2.x*w.x + a2.y*w.y + a2.z*w.z + a2.w*w.w;
            acc3 += a3.x*w.x + a3.y*w.y + a3.z*w.z + a3.w*w.w;
        }
    }
    hid[0][tid] = leaky(acc0);
    hid[1][tid] = leaky(acc1);
    hid[2][tid] = leaky(acc2);
    hid[3][tid] = leaky(acc3);
    __syncthreads();
    int wave = tid >> 6, lane = tid & 63;
    #pragma unroll
    for (int r = 0; r < 3; r++) {
        float p = 0.f;
        #pragma unroll
        for (int q = 0; q < 4; q++) {
            int k = lane + q*64;
            p += hid[wave][k] * ow2[r*256 + k];
        }
        for (int off = 32; off; off >>= 1) p += __shfl_down(p, off);
        if (lane == 0) osh[wave][r] = p + ob2[r];
    }
    __syncthreads();
    if (tid < 4) {
        int b = b0 + tid;
        float o0 = osh[tid][0], o1 = osh[tid][1], o2 = osh[tid][2];
        float sp = (o2 > 20.f ? o2 : log1pf(expf(o2))) + 0.001f;
        float* op = outputs + ((size_t)b*TT + t)*3;
        op[0] = o0; op[1] = o1; op[2] = sp;
        pos[2*b]   += o0;
        pos[2*b+1] += o1;
        cur[3*b] = o0; cur[3*b+1] = o1; cur[3*b+2] = sp;
    }
}

extern "C" void kernel_launch(void* const* d_in, const int* in_sizes, int n_in,
                              void* d_out, int out_size, void* d_ws, size_t ws_size,
                              hipStream_t stream)
{
    const float* start  = (const float*)d_in[0];
    const float* end    = (const float*)d_in[1];
    const float* z      = (const float*)d_in[2];
    const float* ce_w1  = (const float*)d_in[3];
    const float* ce_b1  = (const float*)d_in[4];
    const float* ce_g1  = (const float*)d_in[5];
    const float* ce_be1 = (const float*)d_in[6];
    const float* ce_w2  = (const float*)d_in[7];
    const float* ce_b2  = (const float*)d_in[8];
    const float* ce_g2  = (const float*)d_in[9];
    const float* ce_be2 = (const float*)d_in[10];
    const float* Wih0   = (const float*)d_in[11];
    const float* Whh0   = (const float*)d_in[12];
    const float* bih0   = (const float*)d_in[13];
    const float* bhh0   = (const float*)d_in[14];
    const float* Wih1   = (const float*)d_in[15];
    const float* Whh1   = (const float*)d_in[16];
    const float* bih1   = (const float*)d_in[17];
    const float* bhh1   = (const float*)d_in[18];
    const float* ow1    = (const float*)d_in[19];
    const float* ob1    = (const float*)d_in[20];
    const float* ow2    = (const float*)d_in[21];
    const float* ob2    = (const float*)d_in[22];
    const float* init_in= (const float*)d_in[23];
    const int*   max_len= (const int*)d_in[24];

    float* out = (float*)d_out;
    float* ws  = (float*)d_ws;
    size_t off = 0;
    float* cond = ws + off; off += (size_t)BB*HH;          // 131072
    float* gs0  = ws + off; off += (size_t)BB*G4;          // 524288
    float* c0b[2]; c0b[0] = ws + off; off += (size_t)BB*HH; c0b[1] = ws + off; off += (size_t)BB*HH;
    float* c1b[2]; c1b[0] = ws + off; off += (size_t)BB*HH; c1b[1] = ws + off; off += (size_t)BB*HH;
    float* h1f  = ws + off; off += (size_t)BB*HH;          // fp32 h1 for head
    float* Wf   = ws + off; off += (size_t)G4*8;
    float* pos  = ws + off; off += 512;
    float* cur  = ws + off; off += 1024;                   // pad to 16B multiples
    unsigned short* h0u[2];
    h0u[0] = (unsigned short*)(ws + off); off += (size_t)BB*HH/2;
    h0u[1] = (unsigned short*)(ws + off); off += (size_t)BB*HH/2;
    unsigned short* h1u[2];
    h1u[0] = (unsigned short*)(ws + off); off += (size_t)BB*HH/2;
    h1u[1] = (unsigned short*)(ws + off); off += (size_t)BB*HH/2;
    unsigned short* w0b = (unsigned short*)(ws + off); off += (size_t)G4*HH/2;
    unsigned short* w1b = (unsigned short*)(ws + off); off += (size_t)G4*HH/2;
    unsigned short* w2b = (unsigned short*)(ws + off); off += (size_t)G4*HH/2;

    prep_weights<<<dim3((G4*HH + 255)/256), dim3(256), 0, stream>>>(
        Whh0, Wih1, Whh1, Wih0, w0b, w1b, w2b, Wf);
    init_kernel<<<dim3((BB*HH + 255)/256), dim3(256), 0, stream>>>(
        start, init_in, max_len, c0b[0], c1b[0], h0u[0], h1u[0], pos, cur,
        out + (size_t)BB*TT*3);
    cond_encoder<<<dim3(BB), dim3(256), 0, stream>>>(
        start, end, z, ce_w1, ce_b1, ce_g1, ce_be1, ce_w2, ce_b2, ce_g2, ce_be2, cond);
    static_gates<<<dim3(16, 128), dim3(256), 0, stream>>>(cond, Wih0, bih0, bhh0, gs0);

    for (int t = 0; t < TT; t++) {
        int p = t & 1, np = p ^ 1;
        lstm0_mfma<<<dim3(16, 32), dim3(256), 0, stream>>>(
            w0b, gs0, Wf, end, pos, cur, h0u[p], c0b[p], c0b[np], h0u[np]);
        lstm1_mfma<<<dim3(16, 32), dim3(256), 0, stream>>>(
            w1b, w2b, bih1, bhh1, h0u[np], h1u[p], c1b[p], c1b[np], h1u[np], h1f);
        head_kernel<<<dim3(64), dim3(256), 0, stream>>>(
            h1f, ow1, ob1, ow2, ob2, out, pos, cur, t);
    }
}